// Round 1
// baseline (20752.983 us; speedup 1.0000x reference)
//
#include <hip/hip_runtime.h>
#include <hip/hip_bf16.h>
#include <math.h>

#define Bb 64
#define Tt 512
#define Dd 1024
#define Uu 1024

typedef __attribute__((ext_vector_type(8))) short bf16x8;
typedef __attribute__((ext_vector_type(4))) float f32x4;

// ---- one-time conversions ------------------------------------------------

__global__ void cast_x_bf16(const float* __restrict__ in, __hip_bfloat16* __restrict__ out, int n4) {
  int i = blockIdx.x * blockDim.x + threadIdx.x;
  int stride = gridDim.x * blockDim.x;
  for (; i < n4; i += stride) {
    float4 v = reinterpret_cast<const float4*>(in)[i];
    __hip_bfloat16* o = out + 4 * (size_t)i;
    o[0] = __float2bfloat16(v.x);
    o[1] = __float2bfloat16(v.y);
    o[2] = __float2bfloat16(v.z);
    o[3] = __float2bfloat16(v.w);
  }
}

// in: fp32 [K][N]  ->  out: bf16 [N][K]   (transpose + downcast, 32x32 LDS tiles)
__global__ void transpose_cast_bf16(const float* __restrict__ in, __hip_bfloat16* __restrict__ out,
                                    int K, int N) {
  __shared__ float tile[32][33];
  int n0 = blockIdx.x * 32, k0 = blockIdx.y * 32;
  int tx = threadIdx.x, ty = threadIdx.y;
#pragma unroll
  for (int p = 0; p < 4; ++p) {
    int r = ty + p * 8;
    tile[r][tx] = in[(size_t)(k0 + r) * N + n0 + tx];
  }
  __syncthreads();
#pragma unroll
  for (int p = 0; p < 4; ++p) {
    int r = ty + p * 8;
    out[(size_t)(n0 + r) * K + k0 + tx] = __float2bfloat16(tile[tx][r]);
  }
}

__global__ void init_hc(const float* __restrict__ h0, const float* __restrict__ c0,
                        __hip_bfloat16* __restrict__ hb, float* __restrict__ cws, int n) {
  int i = blockIdx.x * blockDim.x + threadIdx.x;
  if (i < n) {
    hb[i] = __float2bfloat16(h0[i]);
    cws[i] = c0[i];
  }
}

// ---- one recurrence step -------------------------------------------------
// grid = 64 WGs x 256 threads. WG j owns u in [j*16, j*16+16).
// wave g (0..3) computes gate g's pre-activation z[64 x 16] with
// mfma_f32_16x16x32_bf16, K = D (x part) + U (h part) = 2048.
// A-frag: lane l -> row (l&15), k = (l>>4)*8..+7  (16B contiguous)
// B-frag: lane l -> col (l&15), same k            (16B contiguous in W^T rows)
// C/D:    col = lane&15, row = (lane>>4)*4 + reg  [measured m89/m91]
__launch_bounds__(256)
__global__ void lstm_step(const __hip_bfloat16* __restrict__ xb,
                          const __hip_bfloat16* __restrict__ WxT,
                          const __hip_bfloat16* __restrict__ WhT,
                          const float* __restrict__ bias,
                          const float* __restrict__ c0,
                          const __hip_bfloat16* __restrict__ h_cur,
                          __hip_bfloat16* __restrict__ h_nxt,
                          float* __restrict__ c_ws,
                          float* __restrict__ out,
                          int t) {
  __shared__ float z_lds[4][64][16];
  const int tid = threadIdx.x;
  const int wave = tid >> 6;
  const int lane = tid & 63;
  const int l15 = lane & 15;
  const int lk = lane >> 4;
  const int j = blockIdx.x;
  const int col = wave * Uu + j * 16 + l15;  // global column in [0, 4U)

  f32x4 acc[4];
#pragma unroll
  for (int r = 0; r < 4; ++r) acc[r] = (f32x4){0.f, 0.f, 0.f, 0.f};

  // z += x_t @ Wx
  {
    const __hip_bfloat16* bW = WxT + (size_t)col * Dd;
    for (int kc = 0; kc < Dd / 32; ++kc) {
      int k = kc * 32 + lk * 8;
      bf16x8 bfrag = *reinterpret_cast<const bf16x8*>(bW + k);
#pragma unroll
      for (int r = 0; r < 4; ++r) {
        int m = r * 16 + l15;  // batch row
        bf16x8 afrag = *reinterpret_cast<const bf16x8*>(xb + ((size_t)m * Tt + t) * Dd + k);
        acc[r] = __builtin_amdgcn_mfma_f32_16x16x32_bf16(afrag, bfrag, acc[r], 0, 0, 0);
      }
    }
  }
  // z += h @ Wh
  {
    const __hip_bfloat16* bW = WhT + (size_t)col * Uu;
    for (int kc = 0; kc < Uu / 32; ++kc) {
      int k = kc * 32 + lk * 8;
      bf16x8 bfrag = *reinterpret_cast<const bf16x8*>(bW + k);
#pragma unroll
      for (int r = 0; r < 4; ++r) {
        int m = r * 16 + l15;
        bf16x8 afrag = *reinterpret_cast<const bf16x8*>(h_cur + (size_t)m * Uu + k);
        acc[r] = __builtin_amdgcn_mfma_f32_16x16x32_bf16(afrag, bfrag, acc[r], 0, 0, 0);
      }
    }
  }

#pragma unroll
  for (int r = 0; r < 4; ++r)
#pragma unroll
    for (int q = 0; q < 4; ++q)
      z_lds[wave][r * 16 + lk * 4 + q][l15] = acc[r][q];
  __syncthreads();

  // gates: 64 b x 16 u elements, all 4 gate columns local to this WG
  for (int e = tid; e < Bb * 16; e += 256) {
    int b = e >> 4, uu = e & 15;
    int u = j * 16 + uu;
    float zi = z_lds[0][b][uu] + bias[u];
    float zf = z_lds[1][b][uu] + bias[Uu + u];
    float zg = z_lds[2][b][uu] + bias[2 * Uu + u];
    float zo = z_lds[3][b][uu] + bias[3 * Uu + u];
    float ig = 1.f / (1.f + expf(-zi));
    float fg = 1.f / (1.f + expf(-zf));
    float gg = tanhf(zg);
    float og = 1.f / (1.f + expf(-zo));
    int idx = b * Uu + u;
    float cp = (t == 0) ? c0[idx] : c_ws[idx];
    float cn = fg * cp + ig * gg;
    c_ws[idx] = cn;
    float hn = og * tanhf(cn);
    out[((size_t)b * Tt + t) * Uu + u] = hn;
    h_nxt[idx] = __float2bfloat16(hn);
  }
}

// ---- launch --------------------------------------------------------------

extern "C" void kernel_launch(void* const* d_in, const int* in_sizes, int n_in,
                              void* d_out, int out_size, void* d_ws, size_t ws_size,
                              hipStream_t stream) {
  const float* x = (const float*)d_in[0];
  const float* h0 = (const float*)d_in[1];
  const float* c0 = (const float*)d_in[2];
  const float* Wx = (const float*)d_in[3];
  const float* Wh = (const float*)d_in[4];
  const float* bias = (const float*)d_in[5];
  float* out = (float*)d_out;

  char* ws = (char*)d_ws;
  size_t off = 0;
  __hip_bfloat16* xb = (__hip_bfloat16*)(ws + off);  off += (size_t)Bb * Tt * Dd * 2;  // 64 MB
  __hip_bfloat16* WxT = (__hip_bfloat16*)(ws + off); off += (size_t)4 * Uu * Dd * 2;   // 8 MB
  __hip_bfloat16* WhT = (__hip_bfloat16*)(ws + off); off += (size_t)4 * Uu * Uu * 2;   // 8 MB
  __hip_bfloat16* hb = (__hip_bfloat16*)(ws + off);  off += (size_t)2 * Bb * Uu * 2;   // 256 KB (ping-pong)
  float* cws = (float*)(ws + off);                   off += (size_t)Bb * Uu * 4;       // 256 KB

  cast_x_bf16<<<4096, 256, 0, stream>>>(x, xb, Bb * Tt * Dd / 4);
  transpose_cast_bf16<<<dim3(4 * Uu / 32, Dd / 32), dim3(32, 8), 0, stream>>>(Wx, WxT, Dd, 4 * Uu);
  transpose_cast_bf16<<<dim3(4 * Uu / 32, Uu / 32), dim3(32, 8), 0, stream>>>(Wh, WhT, Uu, 4 * Uu);
  init_hc<<<(Bb * Uu + 255) / 256, 256, 0, stream>>>(h0, c0, hb, cws, Bb * Uu);

  for (int t = 0; t < Tt; ++t) {
    const __hip_bfloat16* hc = hb + (size_t)(t & 1) * (Bb * Uu);
    __hip_bfloat16* hn = hb + (size_t)((t + 1) & 1) * (Bb * Uu);
    lstm_step<<<64, 256, 0, stream>>>(xb, WxT, WhT, bias, c0, hc, hn, cws, out, t);
  }
}

// Round 2
// 13277.243 us; speedup vs baseline: 1.5630x; 1.5630x over previous
//
#include <hip/hip_runtime.h>
#include <hip/hip_bf16.h>
#include <math.h>

#define Bb 64
#define Tt 512
#define Dd 1024
#define Uu 1024
#define NWG 128      // persistent workgroups
#define UPW 8        // u's per WG
#define NCOL 32      // packed cols per WG = 4 gates * UPW
#define KTOT 2048    // D + U
#define KW 512       // K-slice per wave

typedef __attribute__((ext_vector_type(8))) short bf16x8;
typedef __attribute__((ext_vector_type(4))) float f32x4;

// ---- one-time prep -------------------------------------------------------

__global__ void cast_x_bf16(const float* __restrict__ in, __hip_bfloat16* __restrict__ out, int n4) {
  int i = blockIdx.x * blockDim.x + threadIdx.x;
  int stride = gridDim.x * blockDim.x;
  for (; i < n4; i += stride) {
    float4 v = reinterpret_cast<const float4*>(in)[i];
    __hip_bfloat16* o = out + 4 * (size_t)i;
    o[0] = __float2bfloat16(v.x);
    o[1] = __float2bfloat16(v.y);
    o[2] = __float2bfloat16(v.z);
    o[3] = __float2bfloat16(v.w);
  }
}

// in: fp32 [1024][4096] (Wx or Wh). Writes transposed+packed bf16 into
// pWT[j][pc][k] where col = g*1024 + j*8 + uu, pc = g*8+uu, k += koff.
__global__ void pack_w(const float* __restrict__ in, __hip_bfloat16* __restrict__ pWT, int koff) {
  __shared__ float tile[32][33];
  int n0 = blockIdx.x * 32, k0 = blockIdx.y * 32;
  int tx = threadIdx.x, ty = threadIdx.y;
#pragma unroll
  for (int p = 0; p < 4; ++p) {
    int r = ty + p * 8;
    tile[r][tx] = in[(size_t)(k0 + r) * (4 * Uu) + n0 + tx];
  }
  __syncthreads();
#pragma unroll
  for (int p = 0; p < 4; ++p) {
    int r = ty + p * 8;
    int col = n0 + r;
    int j = (col & (Uu - 1)) >> 3;
    int g = col >> 10;
    int uu = col & 7;
    pWT[((size_t)(j * NCOL + g * UPW + uu)) * KTOT + koff + k0 + tx] = __float2bfloat16(tile[tx][r]);
  }
}

// ---- device-scope grid barrier ------------------------------------------

__device__ inline void gbar(unsigned* bar) {
  __syncthreads();
  if (threadIdx.x == 0) {
    __threadfence();
    unsigned g = __hip_atomic_load(&bar[1], __ATOMIC_RELAXED, __HIP_MEMORY_SCOPE_AGENT);
    unsigned a = __hip_atomic_fetch_add(&bar[0], 1u, __ATOMIC_ACQ_REL, __HIP_MEMORY_SCOPE_AGENT);
    if (a == NWG - 1u) {
      __hip_atomic_store(&bar[0], 0u, __ATOMIC_RELAXED, __HIP_MEMORY_SCOPE_AGENT);
      __hip_atomic_fetch_add(&bar[1], 1u, __ATOMIC_RELEASE, __HIP_MEMORY_SCOPE_AGENT);
    } else {
      while (__hip_atomic_load(&bar[1], __ATOMIC_ACQUIRE, __HIP_MEMORY_SCOPE_AGENT) == g)
        __builtin_amdgcn_s_sleep(2);
    }
    __threadfence();
  }
  __syncthreads();
}

// ---- persistent LSTM -----------------------------------------------------
// 128 WGs x 256 thr. WG j owns u in [j*8, j*8+8) -> 32 packed cols (4 gates).
// Wave ks holds weight slice K=[ks*512, ks*512+512) in 128 VGPRs; waves 0,1
// cover the x@Wx part of K, waves 2,3 the h@Wh part. Partials reduced in LDS.
// c: 2 floats/thread in regs. h: ping-pong bf16 global. One grid barrier/step.
__launch_bounds__(256, 1)
__global__ void lstm_persist(const __hip_bfloat16* __restrict__ xb,
                             const __hip_bfloat16* __restrict__ pWT,
                             const float* __restrict__ bias,
                             const float* __restrict__ h0,
                             const float* __restrict__ c0,
                             __hip_bfloat16* __restrict__ hb,  // [2][B][U]
                             float* __restrict__ out,
                             unsigned* __restrict__ bar) {
  const int tid = threadIdx.x;
  const int wave = tid >> 6;
  const int lane = tid & 63;
  const int l15 = lane & 15;
  const int lk = lane >> 4;
  const int j = blockIdx.x;

  __shared__ float zpart[4][Bb][NCOL + 1];  // +1 pad vs bank conflicts

  // --- load this wave's weight slice into registers (held all 512 steps)
  bf16x8 wreg[2][16];
  {
    const __hip_bfloat16* wp = pWT + (size_t)j * NCOL * KTOT;
#pragma unroll
    for (int nt = 0; nt < 2; ++nt)
#pragma unroll
      for (int kk = 0; kk < 16; ++kk) {
        int pc = nt * 16 + l15;
        int k = wave * KW + kk * 32 + lk * 8;
        wreg[nt][kk] = *reinterpret_cast<const bf16x8*>(wp + (size_t)pc * KTOT + k);
      }
  }

  // --- per-thread epilogue state: elements (b0,u0) and (b0+32,u0)
  const int b0 = tid >> 3;
  const int uu0 = tid & 7;
  const int u0 = j * UPW + uu0;
  const float bi_i = bias[0 * Uu + u0];
  const float bi_f = bias[1 * Uu + u0];
  const float bi_g = bias[2 * Uu + u0];
  const float bi_o = bias[3 * Uu + u0];
  float cr0 = c0[(size_t)b0 * Uu + u0];
  float cr1 = c0[(size_t)(b0 + 32) * Uu + u0];

  // init h ping buffer 0 (each WG covers its own u slice, all b)
  hb[(size_t)b0 * Uu + u0] = __float2bfloat16(h0[(size_t)b0 * Uu + u0]);
  hb[(size_t)(b0 + 32) * Uu + u0] = __float2bfloat16(h0[(size_t)(b0 + 32) * Uu + u0]);
  gbar(bar);

  for (int t = 0; t < Tt; ++t) {
    const __hip_bfloat16* hcur = hb + (size_t)(t & 1) * (Bb * Uu);
    __hip_bfloat16* hnxt = hb + (size_t)((t + 1) & 1) * (Bb * Uu);

    // --- MFMA phase: z_partial[64 x 32] over this wave's K-slice
    const __hip_bfloat16* asrc;
    size_t mstride;
    int kofs;
    if (wave < 2) {
      asrc = xb + (size_t)t * Dd;
      mstride = (size_t)Tt * Dd;
      kofs = wave * KW;
    } else {
      asrc = hcur;
      mstride = Uu;
      kofs = (wave - 2) * KW;
    }

    f32x4 acc[4][2];
#pragma unroll
    for (int mt = 0; mt < 4; ++mt)
#pragma unroll
      for (int nt = 0; nt < 2; ++nt) acc[mt][nt] = (f32x4){0.f, 0.f, 0.f, 0.f};

#pragma unroll
    for (int kk = 0; kk < 16; ++kk) {
      bf16x8 af[4];
#pragma unroll
      for (int mt = 0; mt < 4; ++mt) {
        int m = mt * 16 + l15;
        af[mt] = *reinterpret_cast<const bf16x8*>(asrc + (size_t)m * mstride + kofs + kk * 32 + lk * 8);
      }
#pragma unroll
      for (int mt = 0; mt < 4; ++mt) {
        acc[mt][0] = __builtin_amdgcn_mfma_f32_16x16x32_bf16(af[mt], wreg[0][kk], acc[mt][0], 0, 0, 0);
        acc[mt][1] = __builtin_amdgcn_mfma_f32_16x16x32_bf16(af[mt], wreg[1][kk], acc[mt][1], 0, 0, 0);
      }
    }

    // C/D layout: col = lane&15, row = (lane>>4)*4 + q
#pragma unroll
    for (int mt = 0; mt < 4; ++mt)
#pragma unroll
      for (int nt = 0; nt < 2; ++nt)
#pragma unroll
        for (int q = 0; q < 4; ++q)
          zpart[wave][mt * 16 + lk * 4 + q][nt * 16 + l15] = acc[mt][nt][q];
    __syncthreads();

    // --- reduce 4 K-slices + gates for (b0,u0) and (b0+32,u0)
    float z0[4], z1[4];
#pragma unroll
    for (int g = 0; g < 4; ++g) {
      int cc = g * UPW + uu0;
      z0[g] = zpart[0][b0][cc] + zpart[1][b0][cc] + zpart[2][b0][cc] + zpart[3][b0][cc];
      z1[g] = zpart[0][b0 + 32][cc] + zpart[1][b0 + 32][cc] + zpart[2][b0 + 32][cc] + zpart[3][b0 + 32][cc];
    }
    {
      float ig = 1.f / (1.f + __expf(-(z0[0] + bi_i)));
      float fg = 1.f / (1.f + __expf(-(z0[1] + bi_f)));
      float gg = tanhf(z0[2] + bi_g);
      float og = 1.f / (1.f + __expf(-(z0[3] + bi_o)));
      cr0 = fg * cr0 + ig * gg;
      float hv = og * tanhf(cr0);
      out[((size_t)b0 * Tt + t) * Uu + u0] = hv;
      hnxt[(size_t)b0 * Uu + u0] = __float2bfloat16(hv);
    }
    {
      float ig = 1.f / (1.f + __expf(-(z1[0] + bi_i)));
      float fg = 1.f / (1.f + __expf(-(z1[1] + bi_f)));
      float gg = tanhf(z1[2] + bi_g);
      float og = 1.f / (1.f + __expf(-(z1[3] + bi_o)));
      cr1 = fg * cr1 + ig * gg;
      float hv = og * tanhf(cr1);
      out[((size_t)(b0 + 32) * Tt + t) * Uu + u0] = hv;
      hnxt[(size_t)(b0 + 32) * Uu + u0] = __float2bfloat16(hv);
    }

    gbar(bar);  // publish h_next (incl. __threadfence), reuse zpart safely
  }
}

// ---- launch --------------------------------------------------------------

extern "C" void kernel_launch(void* const* d_in, const int* in_sizes, int n_in,
                              void* d_out, int out_size, void* d_ws, size_t ws_size,
                              hipStream_t stream) {
  const float* x = (const float*)d_in[0];
  const float* h0 = (const float*)d_in[1];
  const float* c0 = (const float*)d_in[2];
  const float* Wx = (const float*)d_in[3];
  const float* Wh = (const float*)d_in[4];
  const float* bias = (const float*)d_in[5];
  float* out = (float*)d_out;

  char* ws = (char*)d_ws;
  size_t off = 0;
  __hip_bfloat16* xb = (__hip_bfloat16*)(ws + off);  off += (size_t)Bb * Tt * Dd * 2;       // 64 MB
  __hip_bfloat16* pWT = (__hip_bfloat16*)(ws + off); off += (size_t)NWG * NCOL * KTOT * 2;  // 16 MB
  __hip_bfloat16* hb = (__hip_bfloat16*)(ws + off);  off += (size_t)2 * Bb * Uu * 2;        // 256 KB
  unsigned* bar = (unsigned*)(ws + off);             off += 256;

  cast_x_bf16<<<4096, 256, 0, stream>>>(x, xb, Bb * Tt * Dd / 4);
  pack_w<<<dim3(4 * Uu / 32, Dd / 32), dim3(32, 8), 0, stream>>>(Wx, pWT, 0);
  pack_w<<<dim3(4 * Uu / 32, Uu / 32), dim3(32, 8), 0, stream>>>(Wh, pWT, Dd);
  hipMemsetAsync(bar, 0, 256, stream);

  lstm_persist<<<NWG, 256, 0, stream>>>(xb, pWT, bias, h0, c0, hb, out, bar);
}

// Round 3
// 11490.179 us; speedup vs baseline: 1.8061x; 1.1555x over previous
//
#include <hip/hip_runtime.h>
#include <hip/hip_bf16.h>
#include <math.h>

#define Bb 64
#define Tt 512
#define Dd 1024
#define Uu 1024
#define NWG 128      // persistent workgroups
#define UPW 8        // u's per WG
#define NCOL 32      // packed cols per WG = 4 gates * UPW
#define KTOT 2048    // D + U
#define KW 512       // K-slice per wave
#define ZLD (NCOL + 2)  // zpart row stride (even -> 8B aligned, <=2-way banks)

typedef __attribute__((ext_vector_type(8))) short bf16x8;
typedef __attribute__((ext_vector_type(4))) float f32x4;
typedef __attribute__((ext_vector_type(2))) float f32x2;

// ---- one-time prep -------------------------------------------------------

__global__ void cast_x_bf16(const float* __restrict__ in, __hip_bfloat16* __restrict__ out, int n4) {
  int i = blockIdx.x * blockDim.x + threadIdx.x;
  int stride = gridDim.x * blockDim.x;
  for (; i < n4; i += stride) {
    float4 v = reinterpret_cast<const float4*>(in)[i];
    __hip_bfloat16* o = out + 4 * (size_t)i;
    o[0] = __float2bfloat16(v.x);
    o[1] = __float2bfloat16(v.y);
    o[2] = __float2bfloat16(v.z);
    o[3] = __float2bfloat16(v.w);
  }
}

// in: fp32 [K][4096] (Wx or Wh). out packed: pWT[j][pc][k], col=g*1024+j*8+uu, pc=g*8+uu.
__global__ void pack_w(const float* __restrict__ in, __hip_bfloat16* __restrict__ pWT, int koff) {
  __shared__ float tile[32][33];
  int n0 = blockIdx.x * 32, k0 = blockIdx.y * 32;
  int tx = threadIdx.x, ty = threadIdx.y;
#pragma unroll
  for (int p = 0; p < 4; ++p) {
    int r = ty + p * 8;
    tile[r][tx] = in[(size_t)(k0 + r) * (4 * Uu) + n0 + tx];
  }
  __syncthreads();
#pragma unroll
  for (int p = 0; p < 4; ++p) {
    int r = ty + p * 8;
    int col = n0 + r;
    int j = (col & (Uu - 1)) >> 3;
    int g = col >> 10;
    int uu = col & 7;
    pWT[((size_t)(j * NCOL + g * UPW + uu)) * KTOT + koff + k0 + tx] = __float2bfloat16(tile[tx][r]);
  }
}

// ---- fence-free grid barrier (no L2 inv/wb ops in steady state) ----------
// __syncthreads() drains each wave's vmcnt before s_barrier, so all h-stores
// (system-scope write-through) are ack'd at the coherent point before arrival.
__device__ __forceinline__ void gbar_fast(unsigned* bar) {
  __syncthreads();
  if (threadIdx.x == 0) {
    unsigned g = __hip_atomic_load(&bar[1], __ATOMIC_RELAXED, __HIP_MEMORY_SCOPE_SYSTEM);
    unsigned a = __hip_atomic_fetch_add(&bar[0], 1u, __ATOMIC_RELAXED, __HIP_MEMORY_SCOPE_SYSTEM);
    if (a == NWG - 1u) {
      __hip_atomic_store(&bar[0], 0u, __ATOMIC_RELAXED, __HIP_MEMORY_SCOPE_SYSTEM);
      asm volatile("s_waitcnt vmcnt(0)" ::: "memory");  // reset visible before bump
      __hip_atomic_store(&bar[1], g + 1u, __ATOMIC_RELAXED, __HIP_MEMORY_SCOPE_SYSTEM);
    } else {
      while (__hip_atomic_load(&bar[1], __ATOMIC_RELAXED, __HIP_MEMORY_SCOPE_SYSTEM) == g)
        __builtin_amdgcn_s_sleep(2);
    }
  }
  __syncthreads();
}

// ---- persistent LSTM -----------------------------------------------------
// 128 WGs x 256 thr. WG j owns u in [j*8, j*8+8) -> 32 packed cols (4 gates).
// Wave ks holds weight K-slice in regs; waves 0,1 = x@Wx, waves 2,3 = h@Wh.
// h crosses XCDs via system-scope (sc0 sc1) relaxed atomics -> MALL-coherent,
// no cache-maintenance ops anywhere in the loop.
__launch_bounds__(256, 1)
__global__ void lstm_persist(const __hip_bfloat16* __restrict__ xb,
                             const __hip_bfloat16* __restrict__ pWT,
                             const float* __restrict__ bias,
                             const float* __restrict__ h0,
                             const float* __restrict__ c0,
                             __hip_bfloat16* __restrict__ hb,  // [2][B][U]
                             float* __restrict__ out,
                             unsigned* __restrict__ bar) {
  const int tid = threadIdx.x;
  const int wave = tid >> 6;
  const int lane = tid & 63;
  const int l15 = lane & 15;
  const int lk = lane >> 4;
  const int j = blockIdx.x;

  __shared__ float zpart[4][Bb][ZLD];

  // --- weight slice into registers (held all 512 steps)
  bf16x8 wreg[2][16];
  {
    const __hip_bfloat16* wp = pWT + (size_t)j * NCOL * KTOT;
#pragma unroll
    for (int nt = 0; nt < 2; ++nt)
#pragma unroll
      for (int kk = 0; kk < 16; ++kk) {
        int pc = nt * 16 + l15;
        int k = wave * KW + kk * 32 + lk * 8;
        wreg[nt][kk] = *reinterpret_cast<const bf16x8*>(wp + (size_t)pc * KTOT + k);
      }
  }

  // --- epilogue ownership: one batch row, two adjacent u's
  const int eb = tid >> 2;          // 0..63
  const int eu = (tid & 3) * 2;     // 0,2,4,6
  const int u0 = j * UPW + eu;
  float bi0[4], bi1[4];
#pragma unroll
  for (int g = 0; g < 4; ++g) {
    bi0[g] = bias[g * Uu + u0];
    bi1[g] = bias[g * Uu + u0 + 1];
  }
  float cr0 = c0[(size_t)eb * Uu + u0];
  float cr1 = c0[(size_t)eb * Uu + u0 + 1];

  // --- init h buffer 0 (write-through so sc1 readers see it)
  unsigned* hb32 = (unsigned*)hb;
  {
    union { __hip_bfloat162 v; unsigned u; } pk;
    pk.v.x = __float2bfloat16(h0[(size_t)eb * Uu + u0]);
    pk.v.y = __float2bfloat16(h0[(size_t)eb * Uu + u0 + 1]);
    __hip_atomic_store(&hb32[((size_t)eb * Uu + u0) >> 1], pk.u,
                       __ATOMIC_RELAXED, __HIP_MEMORY_SCOPE_SYSTEM);
  }
  gbar_fast(bar);

  for (int t = 0; t < Tt; ++t) {
    const __hip_bfloat16* hcur = hb + (size_t)(t & 1) * (Bb * Uu);
    unsigned* hnxt32 = hb32 + ((size_t)((t + 1) & 1) * (Bb * Uu) >> 1);

    f32x4 acc[4][2];
#pragma unroll
    for (int mt = 0; mt < 4; ++mt)
#pragma unroll
      for (int nt = 0; nt < 2; ++nt) acc[mt][nt] = (f32x4){0.f, 0.f, 0.f, 0.f};

    if (wave < 2) {
      // x part: plain cached loads (x immutable -> never stale)
      const __hip_bfloat16* asrc = xb + (size_t)t * Dd + (size_t)wave * KW;
#pragma unroll
      for (int kk = 0; kk < 16; ++kk) {
        bf16x8 af[4];
#pragma unroll
        for (int mt = 0; mt < 4; ++mt) {
          int m = mt * 16 + l15;
          af[mt] = *reinterpret_cast<const bf16x8*>(asrc + (size_t)m * Tt * Dd + kk * 32 + lk * 8);
        }
#pragma unroll
        for (int mt = 0; mt < 4; ++mt) {
          acc[mt][0] = __builtin_amdgcn_mfma_f32_16x16x32_bf16(af[mt], wreg[0][kk], acc[mt][0], 0, 0, 0);
          acc[mt][1] = __builtin_amdgcn_mfma_f32_16x16x32_bf16(af[mt], wreg[1][kk], acc[mt][1], 0, 0, 0);
        }
      }
    } else {
      // h part: system-scope loads (bypass stale L1/L2, hit coherent MALL)
      const int kofs = (wave - 2) * KW;
#pragma unroll
      for (int kk = 0; kk < 16; ++kk) {
        bf16x8 af[4];
#pragma unroll
        for (int mt = 0; mt < 4; ++mt) {
          int m = mt * 16 + l15;
          const unsigned long long* p =
              (const unsigned long long*)(hcur + (size_t)m * Uu + kofs + kk * 32 + lk * 8);
          union { bf16x8 v; unsigned long long q[2]; } au;
          au.q[0] = __hip_atomic_load(p, __ATOMIC_RELAXED, __HIP_MEMORY_SCOPE_SYSTEM);
          au.q[1] = __hip_atomic_load(p + 1, __ATOMIC_RELAXED, __HIP_MEMORY_SCOPE_SYSTEM);
          af[mt] = au.v;
        }
#pragma unroll
        for (int mt = 0; mt < 4; ++mt) {
          acc[mt][0] = __builtin_amdgcn_mfma_f32_16x16x32_bf16(af[mt], wreg[0][kk], acc[mt][0], 0, 0, 0);
          acc[mt][1] = __builtin_amdgcn_mfma_f32_16x16x32_bf16(af[mt], wreg[1][kk], acc[mt][1], 0, 0, 0);
        }
      }
    }

    // C/D layout: col = lane&15, row = (lane>>4)*4 + q
#pragma unroll
    for (int mt = 0; mt < 4; ++mt)
#pragma unroll
      for (int nt = 0; nt < 2; ++nt)
#pragma unroll
        for (int q = 0; q < 4; ++q)
          zpart[wave][mt * 16 + lk * 4 + q][nt * 16 + l15] = acc[mt][nt][q];
    __syncthreads();

    // --- reduce 4 K-slices + gates for (eb, u0) and (eb, u0+1)
    f32x2 zz[4];
#pragma unroll
    for (int g = 0; g < 4; ++g) {
      f32x2 s = *reinterpret_cast<const f32x2*>(&zpart[0][eb][g * UPW + eu]);
#pragma unroll
      for (int w = 1; w < 4; ++w) {
        f32x2 v = *reinterpret_cast<const f32x2*>(&zpart[w][eb][g * UPW + eu]);
        s.x += v.x; s.y += v.y;
      }
      zz[g] = s;
    }
    float hv0, hv1;
    {
      float ig = 1.f / (1.f + __expf(-(zz[0].x + bi0[0])));
      float fg = 1.f / (1.f + __expf(-(zz[1].x + bi0[1])));
      float gg = tanhf(zz[2].x + bi0[2]);
      float og = 1.f / (1.f + __expf(-(zz[3].x + bi0[3])));
      cr0 = fg * cr0 + ig * gg;
      hv0 = og * tanhf(cr0);
    }
    {
      float ig = 1.f / (1.f + __expf(-(zz[0].y + bi1[0])));
      float fg = 1.f / (1.f + __expf(-(zz[1].y + bi1[1])));
      float gg = tanhf(zz[2].y + bi1[2]);
      float og = 1.f / (1.f + __expf(-(zz[3].y + bi1[3])));
      cr1 = fg * cr1 + ig * gg;
      hv1 = og * tanhf(cr1);
    }
    f32x2 o2 = {hv0, hv1};
    __builtin_nontemporal_store(o2, (f32x2*)(out + ((size_t)eb * Tt + t) * Uu + u0));
    {
      union { __hip_bfloat162 v; unsigned u; } pk;
      pk.v.x = __float2bfloat16(hv0);
      pk.v.y = __float2bfloat16(hv1);
      __hip_atomic_store(&hnxt32[((size_t)eb * Uu + u0) >> 1], pk.u,
                         __ATOMIC_RELAXED, __HIP_MEMORY_SCOPE_SYSTEM);
    }

    gbar_fast(bar);  // publish h_next; also guards zpart reuse
  }
}

// ---- launch --------------------------------------------------------------

extern "C" void kernel_launch(void* const* d_in, const int* in_sizes, int n_in,
                              void* d_out, int out_size, void* d_ws, size_t ws_size,
                              hipStream_t stream) {
  const float* x = (const float*)d_in[0];
  const float* h0 = (const float*)d_in[1];
  const float* c0 = (const float*)d_in[2];
  const float* Wx = (const float*)d_in[3];
  const float* Wh = (const float*)d_in[4];
  const float* bias = (const float*)d_in[5];
  float* out = (float*)d_out;

  char* ws = (char*)d_ws;
  size_t off = 0;
  __hip_bfloat16* xb = (__hip_bfloat16*)(ws + off);  off += (size_t)Bb * Tt * Dd * 2;       // 64 MB
  __hip_bfloat16* pWT = (__hip_bfloat16*)(ws + off); off += (size_t)NWG * NCOL * KTOT * 2;  // 16 MB
  __hip_bfloat16* hb = (__hip_bfloat16*)(ws + off);  off += (size_t)2 * Bb * Uu * 2;        // 256 KB
  unsigned* bar = (unsigned*)(ws + off);             off += 256;

  cast_x_bf16<<<4096, 256, 0, stream>>>(x, xb, Bb * Tt * Dd / 4);
  pack_w<<<dim3(4 * Uu / 32, Dd / 32), dim3(32, 8), 0, stream>>>(Wx, pWT, 0);
  pack_w<<<dim3(4 * Uu / 32, Uu / 32), dim3(32, 8), 0, stream>>>(Wh, pWT, Dd);
  hipMemsetAsync(bar, 0, 256, stream);

  lstm_persist<<<NWG, 256, 0, stream>>>(xb, pWT, bias, h0, c0, hb, out, bar);
}

// Round 4
// 9696.078 us; speedup vs baseline: 2.1403x; 1.1850x over previous
//
#include <hip/hip_runtime.h>
#include <hip/hip_bf16.h>
#include <math.h>

#define Bb 64
#define Tt 512
#define Dd 1024
#define Uu 1024
#define NWG 128      // persistent workgroups
#define UPW 8        // u's per WG
#define NCOL 32      // packed cols per WG = 4 gates * UPW
#define KTOT 2048    // D + U
#define KW 512       // K-slice per wave
#define ZLD (NCOL + 2)

typedef __attribute__((ext_vector_type(8))) short bf16x8;
typedef __attribute__((ext_vector_type(4))) float f32x4;
typedef __attribute__((ext_vector_type(2))) float f32x2;

// ---- one-time prep -------------------------------------------------------

__global__ void cast_x_bf16(const float* __restrict__ in, __hip_bfloat16* __restrict__ out, int n4) {
  int i = blockIdx.x * blockDim.x + threadIdx.x;
  int stride = gridDim.x * blockDim.x;
  for (; i < n4; i += stride) {
    float4 v = reinterpret_cast<const float4*>(in)[i];
    __hip_bfloat16* o = out + 4 * (size_t)i;
    o[0] = __float2bfloat16(v.x);
    o[1] = __float2bfloat16(v.y);
    o[2] = __float2bfloat16(v.z);
    o[3] = __float2bfloat16(v.w);
  }
}

// in: fp32 [K][4096] (Wx or Wh). out packed: pWT[j][pc][k], col=g*1024+j*8+uu, pc=g*8+uu.
__global__ void pack_w(const float* __restrict__ in, __hip_bfloat16* __restrict__ pWT, int koff) {
  __shared__ float tile[32][33];
  int n0 = blockIdx.x * 32, k0 = blockIdx.y * 32;
  int tx = threadIdx.x, ty = threadIdx.y;
#pragma unroll
  for (int p = 0; p < 4; ++p) {
    int r = ty + p * 8;
    tile[r][tx] = in[(size_t)(k0 + r) * (4 * Uu) + n0 + tx];
  }
  __syncthreads();
#pragma unroll
  for (int p = 0; p < 4; ++p) {
    int r = ty + p * 8;
    int col = n0 + r;
    int j = (col & (Uu - 1)) >> 3;
    int g = col >> 10;
    int uu = col & 7;
    pWT[((size_t)(j * NCOL + g * UPW + uu)) * KTOT + koff + k0 + tx] = __float2bfloat16(tile[tx][r]);
  }
}

// ---- persistent LSTM -----------------------------------------------------
// 128 WGs x 256 thr. WG j owns u in [j*8, j*8+8) -> 32 packed cols (4 gates).
// Waves 0,1: x@Wx for step t+1 (no h dependency, overlaps barrier wait).
// Waves 2,3: wait release, then h@Wh for step t via system-scope loads.
// Barrier: per-WG padded arrival flags (plain parallel stores, NO RMW);
// WG0 wave2 polls flags and bumps a release word; only waves 2,3 spin.
__launch_bounds__(256, 1)
__global__ void lstm_persist(const __hip_bfloat16* __restrict__ xb,
                             const __hip_bfloat16* __restrict__ pWT,
                             const float* __restrict__ bias,
                             const float* __restrict__ h0,
                             const float* __restrict__ c0,
                             __hip_bfloat16* __restrict__ hb,  // [2][B][U]
                             float* __restrict__ out,
                             unsigned* __restrict__ flags,     // [NWG][16] 64B-padded
                             unsigned* __restrict__ rel) {
  const int tid = threadIdx.x;
  const int wave = tid >> 6;
  const int lane = tid & 63;
  const int l15 = lane & 15;
  const int lk = lane >> 4;
  const int j = blockIdx.x;

  __shared__ float zx[2][2][Bb][ZLD];  // [buf][wavehalf][b][col]
  __shared__ float zh[2][Bb][ZLD];

  // --- weight slice into registers, pinned (held all 512 steps)
  bf16x8 wreg[2][16];
  {
    const __hip_bfloat16* wp = pWT + (size_t)j * NCOL * KTOT;
#pragma unroll
    for (int nt = 0; nt < 2; ++nt)
#pragma unroll
      for (int kk = 0; kk < 16; ++kk) {
        int pc = nt * 16 + l15;
        int k = wave * KW + kk * 32 + lk * 8;
        wreg[nt][kk] = *reinterpret_cast<const bf16x8*>(wp + (size_t)pc * KTOT + k);
      }
    // pin: opaque touch so the loads can't be sunk into the t-loop
#pragma unroll
    for (int nt = 0; nt < 2; ++nt)
#pragma unroll
      for (int kk = 0; kk < 16; ++kk)
        asm volatile("" : "+v"(wreg[nt][kk]));
  }

  // --- epilogue ownership: one batch row, two adjacent u's
  const int eb = tid >> 2;
  const int eu = (tid & 3) * 2;
  const int u0 = j * UPW + eu;
  float bi0[4], bi1[4];
#pragma unroll
  for (int g = 0; g < 4; ++g) {
    bi0[g] = bias[g * Uu + u0];
    bi1[g] = bias[g * Uu + u0 + 1];
  }
  float cr0 = c0[(size_t)eb * Uu + u0];
  float cr1 = c0[(size_t)eb * Uu + u0 + 1];

  // --- init h buffer 0 (system-scope write-through)
  unsigned* hb32 = (unsigned*)hb;
  {
    union { __hip_bfloat162 v; unsigned u; } pk;
    pk.v.x = __float2bfloat16(h0[(size_t)eb * Uu + u0]);
    pk.v.y = __float2bfloat16(h0[(size_t)eb * Uu + u0 + 1]);
    __hip_atomic_store(&hb32[((size_t)eb * Uu + u0) >> 1], pk.u,
                       __ATOMIC_RELAXED, __HIP_MEMORY_SCOPE_SYSTEM);
  }

  // --- prologue: zx(0) into buffer 0
  if (wave < 2) {
    f32x4 acc[4][2];
#pragma unroll
    for (int mt = 0; mt < 4; ++mt)
#pragma unroll
      for (int nt = 0; nt < 2; ++nt) acc[mt][nt] = (f32x4){0.f, 0.f, 0.f, 0.f};
    const __hip_bfloat16* asrc = xb + (size_t)wave * KW;  // t = 0
#pragma unroll
    for (int kk = 0; kk < 16; ++kk) {
      bf16x8 af[4];
#pragma unroll
      for (int mt = 0; mt < 4; ++mt) {
        int m = mt * 16 + l15;
        af[mt] = *reinterpret_cast<const bf16x8*>(asrc + (size_t)m * Tt * Dd + kk * 32 + lk * 8);
      }
#pragma unroll
      for (int mt = 0; mt < 4; ++mt) {
        acc[mt][0] = __builtin_amdgcn_mfma_f32_16x16x32_bf16(af[mt], wreg[0][kk], acc[mt][0], 0, 0, 0);
        acc[mt][1] = __builtin_amdgcn_mfma_f32_16x16x32_bf16(af[mt], wreg[1][kk], acc[mt][1], 0, 0, 0);
      }
    }
#pragma unroll
    for (int mt = 0; mt < 4; ++mt)
#pragma unroll
      for (int nt = 0; nt < 2; ++nt)
#pragma unroll
        for (int q = 0; q < 4; ++q)
          zx[0][wave][mt * 16 + lk * 4 + q][nt * 16 + l15] = acc[mt][nt][q];
  }

  for (int t = 0; t < Tt; ++t) {
    // drains all waves' vmcnt (h stores visible at coherent point) + LDS settle
    __syncthreads();

    if (j > 0 && tid == 0)
      __hip_atomic_store(&flags[j * 16], (unsigned)(t + 1),
                         __ATOMIC_RELAXED, __HIP_MEMORY_SCOPE_SYSTEM);

    if (wave < 2) {
      // ---- x part for step t+1 (overlaps barrier + h latency)
      const int xt = (t + 1 < Tt) ? t + 1 : Tt - 1;
      f32x4 acc[4][2];
#pragma unroll
      for (int mt = 0; mt < 4; ++mt)
#pragma unroll
        for (int nt = 0; nt < 2; ++nt) acc[mt][nt] = (f32x4){0.f, 0.f, 0.f, 0.f};
      const __hip_bfloat16* asrc = xb + (size_t)xt * Dd + (size_t)wave * KW;
#pragma unroll
      for (int kk = 0; kk < 16; ++kk) {
        bf16x8 af[4];
#pragma unroll
        for (int mt = 0; mt < 4; ++mt) {
          int m = mt * 16 + l15;
          af[mt] = *reinterpret_cast<const bf16x8*>(asrc + (size_t)m * Tt * Dd + kk * 32 + lk * 8);
        }
#pragma unroll
        for (int mt = 0; mt < 4; ++mt) {
          acc[mt][0] = __builtin_amdgcn_mfma_f32_16x16x32_bf16(af[mt], wreg[0][kk], acc[mt][0], 0, 0, 0);
          acc[mt][1] = __builtin_amdgcn_mfma_f32_16x16x32_bf16(af[mt], wreg[1][kk], acc[mt][1], 0, 0, 0);
        }
      }
      float (*zdst)[ZLD] = zx[(t + 1) & 1][wave];
#pragma unroll
      for (int mt = 0; mt < 4; ++mt)
#pragma unroll
        for (int nt = 0; nt < 2; ++nt)
#pragma unroll
          for (int q = 0; q < 4; ++q)
            zdst[mt * 16 + lk * 4 + q][nt * 16 + l15] = acc[mt][nt][q];
    } else {
      // ---- barrier wait, then h part for step t
      if (j == 0 && wave == 2) {
        for (int jj = 1 + lane; jj < NWG; jj += 64)
          while (__hip_atomic_load(&flags[jj * 16], __ATOMIC_RELAXED,
                                   __HIP_MEMORY_SCOPE_SYSTEM) < (unsigned)(t + 1))
            __builtin_amdgcn_s_sleep(1);
        // wave converged -> all flags seen; release
        if (lane == 0)
          __hip_atomic_store(rel, (unsigned)(t + 1),
                             __ATOMIC_RELAXED, __HIP_MEMORY_SCOPE_SYSTEM);
      } else {
        while (__hip_atomic_load(rel, __ATOMIC_RELAXED,
                                 __HIP_MEMORY_SCOPE_SYSTEM) < (unsigned)(t + 1))
          __builtin_amdgcn_s_sleep(1);
      }

      const __hip_bfloat16* hcur = hb + (size_t)(t & 1) * (Bb * Uu);
      const int kofs = (wave - 2) * KW;
      f32x4 acc[4][2];
#pragma unroll
      for (int mt = 0; mt < 4; ++mt)
#pragma unroll
        for (int nt = 0; nt < 2; ++nt) acc[mt][nt] = (f32x4){0.f, 0.f, 0.f, 0.f};
#pragma unroll
      for (int kk = 0; kk < 16; ++kk) {
        bf16x8 af[4];
#pragma unroll
        for (int mt = 0; mt < 4; ++mt) {
          int m = mt * 16 + l15;
          const unsigned long long* p =
              (const unsigned long long*)(hcur + (size_t)m * Uu + kofs + kk * 32 + lk * 8);
          union { bf16x8 v; unsigned long long q[2]; } au;
          au.q[0] = __hip_atomic_load(p, __ATOMIC_RELAXED, __HIP_MEMORY_SCOPE_SYSTEM);
          au.q[1] = __hip_atomic_load(p + 1, __ATOMIC_RELAXED, __HIP_MEMORY_SCOPE_SYSTEM);
          af[mt] = au.v;
        }
#pragma unroll
        for (int mt = 0; mt < 4; ++mt) {
          acc[mt][0] = __builtin_amdgcn_mfma_f32_16x16x32_bf16(af[mt], wreg[0][kk], acc[mt][0], 0, 0, 0);
          acc[mt][1] = __builtin_amdgcn_mfma_f32_16x16x32_bf16(af[mt], wreg[1][kk], acc[mt][1], 0, 0, 0);
        }
      }
      float (*zdst)[ZLD] = zh[wave - 2];
#pragma unroll
      for (int mt = 0; mt < 4; ++mt)
#pragma unroll
        for (int nt = 0; nt < 2; ++nt)
#pragma unroll
          for (int q = 0; q < 4; ++q)
            zdst[mt * 16 + lk * 4 + q][nt * 16 + l15] = acc[mt][nt][q];
    }
    __syncthreads();

    // ---- epilogue(t): reduce zx(t) + zh(t), gates, emit
    unsigned* hnxt32 = hb32 + ((size_t)((t + 1) & 1) * (Bb * Uu) >> 1);
    f32x2 zz[4];
#pragma unroll
    for (int g = 0; g < 4; ++g) {
      int cc = g * UPW + eu;
      f32x2 s = *reinterpret_cast<const f32x2*>(&zx[t & 1][0][eb][cc]);
      f32x2 v1 = *reinterpret_cast<const f32x2*>(&zx[t & 1][1][eb][cc]);
      f32x2 v2 = *reinterpret_cast<const f32x2*>(&zh[0][eb][cc]);
      f32x2 v3 = *reinterpret_cast<const f32x2*>(&zh[1][eb][cc]);
      s.x += v1.x + v2.x + v3.x;
      s.y += v1.y + v2.y + v3.y;
      zz[g] = s;
    }
    float hv0, hv1;
    {
      float ig = 1.f / (1.f + __expf(-(zz[0].x + bi0[0])));
      float fg = 1.f / (1.f + __expf(-(zz[1].x + bi0[1])));
      float gg = tanhf(zz[2].x + bi0[2]);
      float og = 1.f / (1.f + __expf(-(zz[3].x + bi0[3])));
      cr0 = fg * cr0 + ig * gg;
      hv0 = og * tanhf(cr0);
    }
    {
      float ig = 1.f / (1.f + __expf(-(zz[0].y + bi1[0])));
      float fg = 1.f / (1.f + __expf(-(zz[1].y + bi1[1])));
      float gg = tanhf(zz[2].y + bi1[2]);
      float og = 1.f / (1.f + __expf(-(zz[3].y + bi1[3])));
      cr1 = fg * cr1 + ig * gg;
      hv1 = og * tanhf(cr1);
    }
    f32x2 o2 = {hv0, hv1};
    __builtin_nontemporal_store(o2, (f32x2*)(out + ((size_t)eb * Tt + t) * Uu + u0));
    {
      union { __hip_bfloat162 v; unsigned u; } pk;
      pk.v.x = __float2bfloat16(hv0);
      pk.v.y = __float2bfloat16(hv1);
      __hip_atomic_store(&hnxt32[((size_t)eb * Uu + u0) >> 1], pk.u,
                         __ATOMIC_RELAXED, __HIP_MEMORY_SCOPE_SYSTEM);
    }
  }
}

// ---- launch --------------------------------------------------------------

extern "C" void kernel_launch(void* const* d_in, const int* in_sizes, int n_in,
                              void* d_out, int out_size, void* d_ws, size_t ws_size,
                              hipStream_t stream) {
  const float* x = (const float*)d_in[0];
  const float* h0 = (const float*)d_in[1];
  const float* c0 = (const float*)d_in[2];
  const float* Wx = (const float*)d_in[3];
  const float* Wh = (const float*)d_in[4];
  const float* bias = (const float*)d_in[5];
  float* out = (float*)d_out;

  char* ws = (char*)d_ws;
  size_t off = 0;
  __hip_bfloat16* xb = (__hip_bfloat16*)(ws + off);  off += (size_t)Bb * Tt * Dd * 2;       // 64 MB
  __hip_bfloat16* pWT = (__hip_bfloat16*)(ws + off); off += (size_t)NWG * NCOL * KTOT * 2;  // 16 MB
  __hip_bfloat16* hb = (__hip_bfloat16*)(ws + off);  off += (size_t)2 * Bb * Uu * 2;        // 256 KB
  unsigned* flags = (unsigned*)(ws + off);           off += (size_t)NWG * 64;               // 8 KB
  unsigned* rel = (unsigned*)(ws + off);             off += 64;

  cast_x_bf16<<<4096, 256, 0, stream>>>(x, xb, Bb * Tt * Dd / 4);
  pack_w<<<dim3(4 * Uu / 32, Dd / 32), dim3(32, 8), 0, stream>>>(Wx, pWT, 0);
  pack_w<<<dim3(4 * Uu / 32, Uu / 32), dim3(32, 8), 0, stream>>>(Wh, pWT, Dd);
  hipMemsetAsync(flags, 0, (size_t)NWG * 64 + 64, stream);

  lstm_persist<<<NWG, 256, 0, stream>>>(xb, pWT, bias, h0, c0, hb, out, flags, rel);
}